// Round 14
// baseline (2985.954 us; speedup 1.0000x reference)
//
#include <hip/hip_runtime.h>
#include <hip/hip_bf16.h>
#include <math.h>

#define DEV __device__ __forceinline__

DEV float sigmoidf_(float x) { return 1.0f / (1.0f + __expf(-x)); }

// Broadcast lane `lane` (wave-uniform SGPR index) of v to all lanes.
// VALU/SALU path — keeps the gate matvecs OFF the single LDS pipe, which is
// ~80% of R8's runtime (5.4K ds_read_b128/wave x 12cyc x 32 waves/CU).
DEV float RLf(float v, int lane) {
  return __int_as_float(__builtin_amdgcn_readlane(__float_as_int(v), lane));
}

#define R10(OP) OP(0) OP(1) OP(2) OP(3) OP(4) OP(5) OP(6) OP(7) OP(8) OP(9)
#define R11(OP) R10(OP) OP(10)

// Compact A staging (240 used entries of the 22x22 matrix):
#define AROB 0
#define AORB 16
#define AODB 32
#define ADOB 144
#define ANUM 256

#define DOT_ARO() (sA2[AROB+0]*hO0 + sA2[AROB+1]*hO1 + sA2[AROB+2]*hO2 + sA2[AROB+3]*hO3 \
                 + sA2[AROB+4]*hO4 + sA2[AROB+5]*hO5 + sA2[AROB+6]*hO6 + sA2[AROB+7]*hO7 \
                 + sA2[AROB+8]*hO8 + sA2[AROB+9]*hO9)
#define DOT_AOD(i) (sA2[AODB+(i)*11+0]*hD0 + sA2[AODB+(i)*11+1]*hD1 + sA2[AODB+(i)*11+2]*hD2 \
                  + sA2[AODB+(i)*11+3]*hD3 + sA2[AODB+(i)*11+4]*hD4 + sA2[AODB+(i)*11+5]*hD5 \
                  + sA2[AODB+(i)*11+6]*hD6 + sA2[AODB+(i)*11+7]*hD7 + sA2[AODB+(i)*11+8]*hD8 \
                  + sA2[AODB+(i)*11+9]*hD9 + sA2[AODB+(i)*11+10]*hD10)
#define DOT_ADO(i) (sA2[ADOB+(i)*10+0]*hO0 + sA2[ADOB+(i)*10+1]*hO1 + sA2[ADOB+(i)*10+2]*hO2 \
                  + sA2[ADOB+(i)*10+3]*hO3 + sA2[ADOB+(i)*10+4]*hO4 + sA2[ADOB+(i)*10+5]*hO5 \
                  + sA2[ADOB+(i)*10+6]*hO6 + sA2[ADOB+(i)*10+7]*hO7 + sA2[ADOB+(i)*10+8]*hO8 \
                  + sA2[ADOB+(i)*10+9]*hO9)

DEV float gstep(float x, float h, const float* k, const float* rk, const float* bb) {
  const float z  = sigmoidf_(fmaf(x, k[0], bb[0]) + fmaf(h, rk[0], bb[3]));
  const float r  = sigmoidf_(fmaf(x, k[1], bb[1]) + fmaf(h, rk[1], bb[4]));
  const float hh = tanhf(fmaf(x, k[2], bb[2]) + r * fmaf(h, rk[2], bb[5]));
  return z * h + (1.f - z) * hh;
}

// 3 tiny sequential bidirectional GRU chains + softmax + gather -> tp[3][60]
__global__ void __launch_bounds__(64, 1)
temporal_kernel(const float* __restrict__ T, const float* __restrict__ GK,
                const float* __restrict__ GRK, const float* __restrict__ GB,
                const float* __restrict__ WO, const int* __restrict__ IDX,
                float* __restrict__ tp) {
  const int i = threadIdx.x;
  __shared__ float fb[3][75];
  __shared__ float gg[3][75];
  if (i < 3) {
    float k0[3], k1[3], rk0[3], rk1[3];
#pragma unroll
    for (int q = 0; q < 3; ++q) {
      k0[q]  = GK[i * 6 + q];      k1[q]  = GK[i * 6 + 3 + q];
      rk0[q] = GRK[i * 6 + q];     rk1[q] = GRK[i * 6 + 3 + q];
    }
    const float* B0 = GB + i * 12;
    const float* B1 = GB + i * 12 + 6;
    float h = 0.f;
    for (int s = 0; s < 75; ++s) { h = gstep(T[i * 75 + s], h, k0, rk0, B0); fb[i][s] = h; }
    h = 0.f;
    for (int s = 0; s < 75; ++s) { h = gstep(fb[i][74 - s], h, k1, rk1, B1); gg[i][s] = h; }
    const float wo = WO[i];
    float mx = -1e30f;
    for (int s = 0; s < 75; ++s) mx = fmaxf(mx, gg[i][s] * wo);
    float sum = 0.f;
    for (int s = 0; s < 75; ++s) { const float e = __expf(gg[i][s] * wo - mx); fb[i][s] = e; sum += e; }
    const float inv = 1.f / sum;
    for (int j = 0; j < 60; ++j) tp[i * 60 + j] = fb[i][IDX[j]] * inv;
  }
}

// One wave per batch element (64-thr WG, (64,2): the ONLY proven spill-free
// config across 13 rounds). Gate matvecs via v_readlane broadcasts with a
// VARIABLE (SGPR) lane index — compact loops, zero LDS traffic in the hot
// path. This is R5's dataflow at the 128-VGPR tier; R5's 2 ms was entirely
// its 1.35 GB spill at the 64-VGPR tier ((64,4)), not the readlanes.
__global__ void __launch_bounds__(64, 2) ggnn_main(
    const float* __restrict__ X, const float* __restrict__ A,
    const float* __restrict__ WgR, const float* __restrict__ bgR,
    const float* __restrict__ WgO, const float* __restrict__ bgO,
    const float* __restrict__ WgD, const float* __restrict__ bgD,
    const float* __restrict__ WzR, const float* __restrict__ WrR,
    const float* __restrict__ WmR, const float* __restrict__ bmR,
    const float* __restrict__ WzO, const float* __restrict__ WrO,
    const float* __restrict__ WmO, const float* __restrict__ bmO,
    const float* __restrict__ WzD, const float* __restrict__ WrD,
    const float* __restrict__ WmD, const float* __restrict__ bmD,
    const float* __restrict__ W1R, const float* __restrict__ b1R, const float* __restrict__ W2R,
    const float* __restrict__ W1O, const float* __restrict__ b1O, const float* __restrict__ W2O,
    const float* __restrict__ W1D, const float* __restrict__ b1D, const float* __restrict__ W2D,
    const float* __restrict__ tp, float* __restrict__ out) {
  const int b = blockIdx.x;
  const int c = threadIdx.x;  // 0..63, lane = feature column

  __shared__ __align__(16) float sm[1408];  // X stage (880) / score stash (1408)
  __shared__ float sA2[ANUM];               // compact A

  const float* Xb = X + (size_t)b * 880;
  const float* Ab = A + (size_t)b * 484;
  for (int t = c; t < 880; t += 64) sm[t] = Xb[t];
  if (c < 10) {
    sA2[AROB + c] = Ab[1 + c];            // A[0][1+c]
    sA2[AORB + c] = Ab[(1 + c) * 22];     // A[1+c][0]
  }
  for (int t = c; t < 110; t += 64) {
    const int i = t / 11, j = t - i * 11;
    sA2[AODB + t] = Ab[(1 + i) * 22 + 11 + j];
  }
  for (int t = c; t < 110; t += 64) {
    const int i = t / 10, j = t - i * 10;
    sA2[ADOB + t] = Ab[(11 + i) * 22 + 1 + j];
  }
  __syncthreads();

  // ---------------- phase 0: h = tanh(Xg @ Wg + bg) ----------------
  float hR;
#define DECLHO(i) float hO##i;
  R10(DECLHO)
#undef DECLHO
#define DECLHD(i) float hD##i;
  R11(DECLHD)
#undef DECLHD
  {
    float aR = bgR[c], cO = bgO[c], cD = bgD[c];
#pragma unroll 4
    for (int k = 0; k < 40; ++k) {
      const float x = sm[k];
      aR = fmaf(x, WgR[k * 64 + c], aR);
      cO = fmaf(x, WgO[k * 64 + c], cO);
      cD = fmaf(x, WgD[k * 64 + c], cD);
    }
    hR = tanhf(aR);
#define DECLAO(i) float aO##i = cO;
    R10(DECLAO)
#undef DECLAO
#define DECLAD(i) float aD##i = cD;
    R11(DECLAD)
#undef DECLAD
#pragma unroll 2
    for (int k = 0; k < 30; ++k) {
      const float wo_ = WgO[(40 + k) * 64 + c];
      const float wd_ = WgD[(40 + k) * 64 + c];
#define AOSTEP(i) aO##i = fmaf(sm[(1 + i) * 40 + 10 + k], wo_, aO##i);
      R10(AOSTEP)
#undef AOSTEP
#define ADSTEP(i) aD##i = fmaf(sm[(11 + i) * 40 + 10 + k], wd_, aD##i);
      R11(ADSTEP)
#undef ADSTEP
    }
#define TANHO(i) hO##i = tanhf(aO##i);
    R10(TANHO)
#undef TANHO
#define TANHD(i) hD##i = tanhf(aD##i);
    R11(TANHD)
#undef TANHD
  }

  const float bmOc = bmO[c], bmDc = bmD[c], bmRc = bmR[c];

  // ---------------- 3 GRU iterations (all matvecs via readlane) ----------------
  for (int it = 0; it < 3; ++it) {
    // snapshots of messages that depend on OLD hO (gate O overwrites hO)
    const float nR = DOT_ARO();
#define DECLND(i) float nD##i = DOT_ADO(i);
    R11(DECLND)
#undef DECLND
    // nO2 from OLD hD (gate D runs after gate O; hD still old here)
#define DECLNO2(i) float nO2_##i = DOT_AOD(i);
    R10(DECLNO2)
#undef DECLNO2

    // ===== gate O (10 rows, K=192: [hO | aor*hR | nO2]) =====
    {
#define DECLZR(i) float az##i = 0.f, ar##i = 0.f;
      R10(DECLZR)
#undef DECLZR
      // segment 0: k' = k, operand = hO_i
#pragma unroll 4
      for (int k = 0; k < 64; ++k) {
        const float wz = WzO[k * 64 + c], wr = WrO[k * 64 + c];
#define STP(i) { const float s = RLf(hO##i, k); az##i = fmaf(s, wz, az##i); ar##i = fmaf(s, wr, ar##i); }
        R10(STP)
#undef STP
      }
      // segment 1: k' = 64+k, operand = aor_i * hR  (never materialized)
      {
#define DECLAOR(i) const float aor##i = sA2[AORB + i];
        R10(DECLAOR)
#undef DECLAOR
#pragma unroll 4
        for (int k = 0; k < 64; ++k) {
          const float wz = WzO[(64 + k) * 64 + c], wr = WrO[(64 + k) * 64 + c];
          const float s = RLf(hR, k);
          const float uz = s * wz, ur = s * wr;
#define STP(i) { az##i = fmaf(aor##i, uz, az##i); ar##i = fmaf(aor##i, ur, ar##i); }
          R10(STP)
#undef STP
        }
      }
      // segment 2: k' = 128+k, operand = nO2_i
#pragma unroll 4
      for (int k = 0; k < 64; ++k) {
        const float wz = WzO[(128 + k) * 64 + c], wr = WrO[(128 + k) * 64 + c];
#define STP(i) { const float s = RLf(nO2_##i, k); az##i = fmaf(s, wz, az##i); ar##i = fmaf(s, wr, ar##i); }
        R10(STP)
#undef STP
      }
#define SIGZR(i) const float z##i = sigmoidf_(az##i); const float hro##i = hO##i * sigmoidf_(ar##i);
      R10(SIGZR)
#undef SIGZR
#define DECLAM(i) float am##i = bmOc;
      R10(DECLAM)
#undef DECLAM
      // m pass, segment 0: operand = hro_i
#pragma unroll 4
      for (int k = 0; k < 64; ++k) {
        const float wm = WmO[k * 64 + c];
#define STP(i) { const float s = RLf(hro##i, k); am##i = fmaf(s, wm, am##i); }
        R10(STP)
#undef STP
      }
      // m pass, segment 1: operand = aor_i * hR
      {
#define DECLAOR(i) const float aor##i = sA2[AORB + i];
        R10(DECLAOR)
#undef DECLAOR
#pragma unroll 4
        for (int k = 0; k < 64; ++k) {
          const float wm = WmO[(64 + k) * 64 + c];
          const float u = RLf(hR, k) * wm;
#define STP(i) { am##i = fmaf(aor##i, u, am##i); }
          R10(STP)
#undef STP
        }
      }
      // m pass, segment 2: operand = nO2_i
#pragma unroll 4
      for (int k = 0; k < 64; ++k) {
        const float wm = WmO[(128 + k) * 64 + c];
#define STP(i) { const float s = RLf(nO2_##i, k); am##i = fmaf(s, wm, am##i); }
        R10(STP)
#undef STP
      }
#define UPDO(i) hO##i = (1.f - z##i) * hO##i + z##i * tanhf(am##i);
      R10(UPDO)
#undef UPDO
    }

    // ===== gate D (11 rows, K=128: [hD | nD]) =====
    {
#define DECLZR(i) float az##i = 0.f, ar##i = 0.f;
      R11(DECLZR)
#undef DECLZR
#pragma unroll 4
      for (int k = 0; k < 64; ++k) {
        const float wz = WzD[k * 64 + c], wr = WrD[k * 64 + c];
#define STP(i) { const float s = RLf(hD##i, k); az##i = fmaf(s, wz, az##i); ar##i = fmaf(s, wr, ar##i); }
        R11(STP)
#undef STP
      }
#pragma unroll 4
      for (int k = 0; k < 64; ++k) {
        const float wz = WzD[(64 + k) * 64 + c], wr = WrD[(64 + k) * 64 + c];
#define STP(i) { const float s = RLf(nD##i, k); az##i = fmaf(s, wz, az##i); ar##i = fmaf(s, wr, ar##i); }
        R11(STP)
#undef STP
      }
#define SIGZR(i) const float z##i = sigmoidf_(az##i); const float hrd##i = hD##i * sigmoidf_(ar##i);
      R11(SIGZR)
#undef SIGZR
#define DECLAM(i) float am##i = bmDc;
      R11(DECLAM)
#undef DECLAM
#pragma unroll 4
      for (int k = 0; k < 64; ++k) {
        const float wm = WmD[k * 64 + c];
#define STP(i) { const float s = RLf(hrd##i, k); am##i = fmaf(s, wm, am##i); }
        R11(STP)
#undef STP
      }
#pragma unroll 4
      for (int k = 0; k < 64; ++k) {
        const float wm = WmD[(64 + k) * 64 + c];
#define STP(i) { const float s = RLf(nD##i, k); am##i = fmaf(s, wm, am##i); }
        R11(STP)
#undef STP
      }
#define UPDD(i) hD##i = (1.f - z##i) * hD##i + z##i * tanhf(am##i);
      R11(UPDD)
#undef UPDD
    }

    // ===== gate R (1 row, K=128: [hR | nR]) =====
    {
      float azR = 0.f, arR = 0.f;
#pragma unroll 4
      for (int k = 0; k < 64; ++k) {
        const float wz0 = WzR[k * 64 + c],        wr0 = WrR[k * 64 + c];
        const float wz1 = WzR[(64 + k) * 64 + c], wr1 = WrR[(64 + k) * 64 + c];
        const float s0 = RLf(hR, k);
        const float s1 = RLf(nR, k);
        azR = fmaf(s0, wz0, azR); arR = fmaf(s0, wr0, arR);
        azR = fmaf(s1, wz1, azR); arR = fmaf(s1, wr1, arR);
      }
      const float zR_ = sigmoidf_(azR);
      const float hrr = hR * sigmoidf_(arR);
      float amR = bmRc;
#pragma unroll 4
      for (int k = 0; k < 64; ++k) {
        const float wm0 = WmR[k * 64 + c], wm1 = WmR[(64 + k) * 64 + c];
        amR = fmaf(RLf(hrr, k), wm0, amR);
        amR = fmaf(RLf(nR, k), wm1, amR);
      }
      hR = (1.f - zR_) * hR + zR_ * tanhf(amR);
    }
  }

  // ---------------- scores ----------------
  __syncthreads();
  sm[c] = hR;
#define STASH_O(i) sm[(1 + i) * 64 + c] = hO##i;
  R10(STASH_O)
#undef STASH_O
#define STASH_D(i) sm[(11 + i) * 64 + c] = hD##i;
  R11(STASH_D)
#undef STASH_D
  __syncthreads();

  const int g = c >> 4;    // row-group 0..3
  const int c1 = c & 15;   // hidden-1 column
  float pR = 0.f, pO = 0.f, pD = 0.f;
  for (int rr = g; rr < 22; rr += 4) {
    const float* W1; const float* b1; const float* W2;
    if (rr == 0)      { W1 = W1R; b1 = b1R; W2 = W2R; }
    else if (rr < 11) { W1 = W1O; b1 = b1O; W2 = W2O; }
    else              { W1 = W1D; b1 = b1D; W2 = W2D; }
    float a = b1[c1];
#pragma unroll 8
    for (int kk = 0; kk < 64; ++kk) {
      const int k = (kk + (g << 4)) & 63;  // stagger to dodge LDS bank aliasing
      a = fmaf(sm[rr * 64 + k], W1[k * 16 + c1], a);
    }
    const float t = tanhf(a) * W2[c1];
    if (rr == 0) pR += t;
    else if (rr < 11) pO += t;
    else pD += t;
  }
#pragma unroll
  for (int off = 32; off >= 1; off >>= 1) {
    pR += __shfl_xor(pR, off, 64);
    pO += __shfl_xor(pO, off, 64);
    pD += __shfl_xor(pD, off, 64);
  }
  if (c < 60) {
    out[(size_t)b * 60 + c] = pR * tp[c] + pO * tp[60 + c] + pD * tp[120 + c];
  }
}

extern "C" void kernel_launch(void* const* d_in, const int* in_sizes, int n_in,
                              void* d_out, int out_size, void* d_ws, size_t ws_size,
                              hipStream_t stream) {
  const float* X   = (const float*)d_in[0];
  const float* A   = (const float*)d_in[1];
  const float* WgR = (const float*)d_in[2];
  const float* bgR = (const float*)d_in[3];
  const float* WgO = (const float*)d_in[4];
  const float* bgO = (const float*)d_in[5];
  const float* WgD = (const float*)d_in[6];
  const float* bgD = (const float*)d_in[7];
  const float* WzR = (const float*)d_in[8];
  const float* WrR = (const float*)d_in[9];
  const float* WmR = (const float*)d_in[10];
  const float* bmR = (const float*)d_in[11];
  const float* WzO = (const float*)d_in[12];
  const float* WrO = (const float*)d_in[13];
  const float* WmO = (const float*)d_in[14];
  const float* bmO = (const float*)d_in[15];
  const float* WzD = (const float*)d_in[16];
  const float* WrD = (const float*)d_in[17];
  const float* WmD = (const float*)d_in[18];
  const float* bmD = (const float*)d_in[19];
  const float* W1R = (const float*)d_in[20];
  const float* b1R = (const float*)d_in[21];
  const float* W2R = (const float*)d_in[22];
  const float* W1O = (const float*)d_in[23];
  const float* b1O = (const float*)d_in[24];
  const float* W2O = (const float*)d_in[25];
  const float* W1D = (const float*)d_in[26];
  const float* b1D = (const float*)d_in[27];
  const float* W2D = (const float*)d_in[28];
  const float* Tmp = (const float*)d_in[29];
  const float* GK  = (const float*)d_in[30];
  const float* GRK = (const float*)d_in[31];
  const float* GB  = (const float*)d_in[32];
  const float* WO  = (const float*)d_in[33];
  const int*   IDX = (const int*)d_in[34];

  float* tp = (float*)d_ws;  // 3*60 floats
  const int B = in_sizes[0] / 880;

  hipLaunchKernelGGL(temporal_kernel, dim3(1), dim3(64), 0, stream, Tmp, GK, GRK, GB, WO, IDX, tp);
  hipLaunchKernelGGL(ggnn_main, dim3(B), dim3(64), 0, stream,
                     X, A, WgR, bgR, WgO, bgO, WgD, bgD,
                     WzR, WrR, WmR, bmR, WzO, WrO, WmO, bmO, WzD, WrD, WmD, bmD,
                     W1R, b1R, W2R, W1O, b1O, W2O, W1D, b1D, W2D,
                     tp, (float*)d_out);
}

// Round 15
// 829.079 us; speedup vs baseline: 3.6015x; 3.6015x over previous
//
#include <hip/hip_runtime.h>
#include <hip/hip_bf16.h>
#include <math.h>

#define DEV __device__ __forceinline__

DEV float sigmoidf_(float x) { return 1.0f / (1.0f + __expf(-x)); }

// (slot, row) lists: slot = per-wave accumulator index, row = local gate row
#define L5A(OP) OP(0,0) OP(1,1) OP(2,2) OP(3,3) OP(4,4)
#define L5B(OP) OP(0,5) OP(1,6) OP(2,7) OP(3,8) OP(4,9)
#define L6A(OP) OP(0,0) OP(1,1) OP(2,2) OP(3,3) OP(4,4) OP(5,5)
#define L5D(OP) OP(0,6) OP(1,7) OP(2,8) OP(3,9) OP(4,10)

// Compact A staging (240 used entries of the 22x22 matrix)
#define AROB 0
#define AORB 16
#define AODB 32
#define ADOB 144
#define ANUM 256

DEV float gstep(float x, float h, const float* k, const float* rk, const float* bb) {
  const float z  = sigmoidf_(fmaf(x, k[0], bb[0]) + fmaf(h, rk[0], bb[3]));
  const float r  = sigmoidf_(fmaf(x, k[1], bb[1]) + fmaf(h, rk[1], bb[4]));
  const float hh = tanhf(fmaf(x, k[2], bb[2]) + r * fmaf(h, rk[2], bb[5]));
  return z * h + (1.f - z) * hh;
}

__global__ void __launch_bounds__(64, 1)
temporal_kernel(const float* __restrict__ T, const float* __restrict__ GK,
                const float* __restrict__ GRK, const float* __restrict__ GB,
                const float* __restrict__ WO, const int* __restrict__ IDX,
                float* __restrict__ tp) {
  const int i = threadIdx.x;
  __shared__ float fb[3][75];
  __shared__ float gg[3][75];
  if (i < 3) {
    float k0[3], k1[3], rk0[3], rk1[3];
#pragma unroll
    for (int q = 0; q < 3; ++q) {
      k0[q]  = GK[i * 6 + q];      k1[q]  = GK[i * 6 + 3 + q];
      rk0[q] = GRK[i * 6 + q];     rk1[q] = GRK[i * 6 + 3 + q];
    }
    const float* B0 = GB + i * 12;
    const float* B1 = GB + i * 12 + 6;
    float h = 0.f;
    for (int s = 0; s < 75; ++s) { h = gstep(T[i * 75 + s], h, k0, rk0, B0); fb[i][s] = h; }
    h = 0.f;
    for (int s = 0; s < 75; ++s) { h = gstep(fb[i][74 - s], h, k1, rk1, B1); gg[i][s] = h; }
    const float wo = WO[i];
    float mx = -1e30f;
    for (int s = 0; s < 75; ++s) mx = fmaxf(mx, gg[i][s] * wo);
    float sum = 0.f;
    for (int s = 0; s < 75; ++s) { const float e = __expf(gg[i][s] * wo - mx); fb[i][s] = e; sum += e; }
    const float inv = 1.f / sum;
    for (int j = 0; j < 60; ++j) tp[i * 60 + j] = fb[i][IDX[j]] * inv;
  }
}

// Weight repack (proven in R13): W[K x 64] -> per-k4-block float4 so lane c
// loads its 4 k-values as one dwordx4. ws layout (1KB per k4-block):
// ZR[0..31] RR[32..63] MR[64..95] ZO[96..143] RO[144..191] MO[192..239]
// ZD[240..271] RD[272..303] MD[304..335]
__global__ void __launch_bounds__(64, 1) prep_kernel(
    const float* __restrict__ WzR, const float* __restrict__ WrR, const float* __restrict__ WmR,
    const float* __restrict__ WzO, const float* __restrict__ WrO, const float* __restrict__ WmO,
    const float* __restrict__ WzD, const float* __restrict__ WrD, const float* __restrict__ WmD,
    char* __restrict__ ws) {
  const int fi = blockIdx.x;
  const int c = threadIdx.x;
  const float* W; int base;
  if      (fi <  32) { W = WzR; base = 0;   }
  else if (fi <  64) { W = WrR; base = 32;  }
  else if (fi <  96) { W = WmR; base = 64;  }
  else if (fi < 144) { W = WzO; base = 96;  }
  else if (fi < 192) { W = WrO; base = 144; }
  else if (fi < 240) { W = WmO; base = 192; }
  else if (fi < 272) { W = WzD; base = 240; }
  else if (fi < 304) { W = WrD; base = 272; }
  else               { W = WmD; base = 304; }
  const int kb = fi - base;
  float4 v;
  v.x = W[(kb * 4 + 0) * 64 + c];
  v.y = W[(kb * 4 + 1) * 64 + c];
  v.z = W[(kb * 4 + 2) * 64 + c];
  v.w = W[(kb * 4 + 3) * 64 + c];
  *(float4*)(ws + 1024 + (size_t)fi * 1024 + c * 16) = v;
}

// ---- per-row macro bodies (s=slot, i=local row) ----
#define ZRDECL(s,i) float az##s = 0.f, ar##s = 0.f;
#define AORD(s,i)  const float aor##s = sA2[AORB + (i)];
#define OS0(s,i) { const float4 v = *reinterpret_cast<const float4*>(&hS[(1+(i))*64 + kb*4]); \
  az##s=fmaf(v.x,wz.x,az##s); az##s=fmaf(v.y,wz.y,az##s); az##s=fmaf(v.z,wz.z,az##s); az##s=fmaf(v.w,wz.w,az##s); \
  ar##s=fmaf(v.x,wr.x,ar##s); ar##s=fmaf(v.y,wr.y,ar##s); ar##s=fmaf(v.z,wr.z,ar##s); ar##s=fmaf(v.w,wr.w,ar##s); }
#define OS1(s,i) { az##s=fmaf(aor##s,uz.x,az##s); az##s=fmaf(aor##s,uz.y,az##s); \
  az##s=fmaf(aor##s,uz.z,az##s); az##s=fmaf(aor##s,uz.w,az##s); \
  ar##s=fmaf(aor##s,ur.x,ar##s); ar##s=fmaf(aor##s,ur.y,ar##s); \
  ar##s=fmaf(aor##s,ur.z,ar##s); ar##s=fmaf(aor##s,ur.w,ar##s); }
#define OS2(s,i) { const float4 v = *reinterpret_cast<const float4*>(&nS[(1+(i))*64 + (kb-32)*4]); \
  az##s=fmaf(v.x,wz.x,az##s); az##s=fmaf(v.y,wz.y,az##s); az##s=fmaf(v.z,wz.z,az##s); az##s=fmaf(v.w,wz.w,az##s); \
  ar##s=fmaf(v.x,wr.x,ar##s); ar##s=fmaf(v.y,wr.y,ar##s); ar##s=fmaf(v.z,wr.z,ar##s); ar##s=fmaf(v.w,wr.w,ar##s); }
#define OSIG(s,i) zS##s = sigmoidf_(az##s); const float rr##s = sigmoidf_(ar##s);
#define OGST(s,i) gS[(1+(i))*64+c] = hS[(1+(i))*64+c] * rr##s;
#define OAMD(s,i) aS##s = bmOc;
#define OM0(s,i) { const float4 v = *reinterpret_cast<const float4*>(&gS[(1+(i))*64 + kb*4]); \
  aS##s=fmaf(v.x,wm.x,aS##s); aS##s=fmaf(v.y,wm.y,aS##s); aS##s=fmaf(v.z,wm.z,aS##s); aS##s=fmaf(v.w,wm.w,aS##s); }
#define OM1(s,i) { aS##s=fmaf(aor##s,um.x,aS##s); aS##s=fmaf(aor##s,um.y,aS##s); \
  aS##s=fmaf(aor##s,um.z,aS##s); aS##s=fmaf(aor##s,um.w,aS##s); }
#define OM2(s,i) { const float4 v = *reinterpret_cast<const float4*>(&nS[(1+(i))*64 + (kb-32)*4]); \
  aS##s=fmaf(v.x,wm.x,aS##s); aS##s=fmaf(v.y,wm.y,aS##s); aS##s=fmaf(v.z,wm.z,aS##s); aS##s=fmaf(v.w,wm.w,aS##s); }

#define DS0(s,i) { const float4 v = *reinterpret_cast<const float4*>(&hS[(11+(i))*64 + kb*4]); \
  az##s=fmaf(v.x,wz.x,az##s); az##s=fmaf(v.y,wz.y,az##s); az##s=fmaf(v.z,wz.z,az##s); az##s=fmaf(v.w,wz.w,az##s); \
  ar##s=fmaf(v.x,wr.x,ar##s); ar##s=fmaf(v.y,wr.y,ar##s); ar##s=fmaf(v.z,wr.z,ar##s); ar##s=fmaf(v.w,wr.w,ar##s); }
#define DS1(s,i) { const float4 v = *reinterpret_cast<const float4*>(&nS[(11+(i))*64 + (kb-16)*4]); \
  az##s=fmaf(v.x,wz.x,az##s); az##s=fmaf(v.y,wz.y,az##s); az##s=fmaf(v.z,wz.z,az##s); az##s=fmaf(v.w,wz.w,az##s); \
  ar##s=fmaf(v.x,wr.x,ar##s); ar##s=fmaf(v.y,wr.y,ar##s); ar##s=fmaf(v.z,wr.z,ar##s); ar##s=fmaf(v.w,wr.w,ar##s); }
#define DSIG(s,i) zS##s = sigmoidf_(az##s); const float rr##s = sigmoidf_(ar##s);
#define DGST(s,i) gS[(11+(i))*64+c] = hS[(11+(i))*64+c] * rr##s;
#define DAMD(s,i) aS##s = bmDc;
#define DM0(s,i) { const float4 v = *reinterpret_cast<const float4*>(&gS[(11+(i))*64 + kb*4]); \
  aS##s=fmaf(v.x,wm.x,aS##s); aS##s=fmaf(v.y,wm.y,aS##s); aS##s=fmaf(v.z,wm.z,aS##s); aS##s=fmaf(v.w,wm.w,aS##s); }
#define DM1(s,i) { const float4 v = *reinterpret_cast<const float4*>(&nS[(11+(i))*64 + (kb-16)*4]); \
  aS##s=fmaf(v.x,wm.x,aS##s); aS##s=fmaf(v.y,wm.y,aS##s); aS##s=fmaf(v.z,wm.z,aS##s); aS##s=fmaf(v.w,wm.w,aS##s); }

#define OGATE(LIST) { \
  LIST(ZRDECL) LIST(AORD) \
  _Pragma("unroll 2") for (int kb = 0; kb < 16; ++kb) { \
    const float4 wz = pWzO[kb*64+c], wr = pWrO[kb*64+c]; LIST(OS0) } \
  _Pragma("unroll 2") for (int kb = 16; kb < 32; ++kb) { \
    const float4 wz = pWzO[kb*64+c], wr = pWrO[kb*64+c]; \
    const float4 h0 = *reinterpret_cast<const float4*>(&hS[(kb-16)*4]); \
    float4 uz, ur; \
    uz.x=h0.x*wz.x; uz.y=h0.y*wz.y; uz.z=h0.z*wz.z; uz.w=h0.w*wz.w; \
    ur.x=h0.x*wr.x; ur.y=h0.y*wr.y; ur.z=h0.z*wr.z; ur.w=h0.w*wr.w; \
    LIST(OS1) } \
  _Pragma("unroll 2") for (int kb = 32; kb < 48; ++kb) { \
    const float4 wz = pWzO[kb*64+c], wr = pWrO[kb*64+c]; LIST(OS2) } \
  LIST(OSIG) LIST(OGST) LIST(OAMD) \
  _Pragma("unroll 2") for (int kb = 0; kb < 16; ++kb) { \
    const float4 wm = pWmO[kb*64+c]; LIST(OM0) } \
  _Pragma("unroll 2") for (int kb = 16; kb < 32; ++kb) { \
    const float4 wm = pWmO[kb*64+c]; \
    const float4 h0 = *reinterpret_cast<const float4*>(&hS[(kb-16)*4]); \
    float4 um; um.x=h0.x*wm.x; um.y=h0.y*wm.y; um.z=h0.z*wm.z; um.w=h0.w*wm.w; \
    LIST(OM1) } \
  _Pragma("unroll 2") for (int kb = 32; kb < 48; ++kb) { \
    const float4 wm = pWmO[kb*64+c]; LIST(OM2) } }

#define DGATE(LIST) { \
  LIST(ZRDECL) \
  _Pragma("unroll 2") for (int kb = 0; kb < 16; ++kb) { \
    const float4 wz = pWzD[kb*64+c], wr = pWrD[kb*64+c]; LIST(DS0) } \
  _Pragma("unroll 2") for (int kb = 16; kb < 32; ++kb) { \
    const float4 wz = pWzD[kb*64+c], wr = pWrD[kb*64+c]; LIST(DS1) } \
  LIST(DSIG) LIST(DGST) LIST(DAMD) \
  _Pragma("unroll 2") for (int kb = 0; kb < 16; ++kb) { \
    const float4 wm = pWmD[kb*64+c]; LIST(DM0) } \
  _Pragma("unroll 2") for (int kb = 16; kb < 32; ++kb) { \
    const float4 wm = pWmD[kb*64+c]; LIST(DM1) } }

#define OUPD(s,i) { const float h_ = hS[(1+(i))*64+c]; \
  hS[(1+(i))*64+c] = (1.f - zS##s)*h_ + zS##s*tanhf(aS##s); }
#define DUPD(s,i) { const float h_ = hS[(11+(i))*64+c]; \
  hS[(11+(i))*64+c] = (1.f - zS##s)*h_ + zS##s*tanhf(aS##s); }

#define NSO(s,i) nS[(1+(i))*64+c] = \
  sA2[AODB+(i)*11+0]*hd0 + sA2[AODB+(i)*11+1]*hd1 + sA2[AODB+(i)*11+2]*hd2 + sA2[AODB+(i)*11+3]*hd3 \
+ sA2[AODB+(i)*11+4]*hd4 + sA2[AODB+(i)*11+5]*hd5 + sA2[AODB+(i)*11+6]*hd6 + sA2[AODB+(i)*11+7]*hd7 \
+ sA2[AODB+(i)*11+8]*hd8 + sA2[AODB+(i)*11+9]*hd9 + sA2[AODB+(i)*11+10]*hd10;
#define NSD(s,i) nS[(11+(i))*64+c] = \
  sA2[ADOB+(i)*10+0]*ho0 + sA2[ADOB+(i)*10+1]*ho1 + sA2[ADOB+(i)*10+2]*ho2 + sA2[ADOB+(i)*10+3]*ho3 \
+ sA2[ADOB+(i)*10+4]*ho4 + sA2[ADOB+(i)*10+5]*ho5 + sA2[ADOB+(i)*10+6]*ho6 + sA2[ADOB+(i)*10+7]*ho7 \
+ sA2[ADOB+(i)*10+8]*ho8 + sA2[ADOB+(i)*10+9]*ho9;

// 256 threads = 4 waves COOPERATING on ONE batch element; h state in LDS.
// Row split: w0=O rows0-4, w1=O rows5-9, w2=D rows0-5, w3=D rows6-10 + R.
// Each row owned end-to-end by one wave -> only cross-wave hazard is
// old-h reads vs new-h writes -> exactly 2 __syncthreads per iteration.
// Per-wave live state ~55 regs: fits ANY allocator tier (spill-proof).
__global__ void __launch_bounds__(256) ggnn_main(
    const float* __restrict__ X, const float* __restrict__ A,
    const float* __restrict__ WgR, const float* __restrict__ bgR,
    const float* __restrict__ WgO, const float* __restrict__ bgO,
    const float* __restrict__ WgD, const float* __restrict__ bgD,
    const float* __restrict__ bmR, const float* __restrict__ bmO, const float* __restrict__ bmD,
    const float* __restrict__ W1R, const float* __restrict__ b1R, const float* __restrict__ W2R,
    const float* __restrict__ W1O, const float* __restrict__ b1O, const float* __restrict__ W2O,
    const float* __restrict__ W1D, const float* __restrict__ b1D, const float* __restrict__ W2D,
    const char* __restrict__ ws, const float* __restrict__ tp,
    float* __restrict__ out) {
  const int b = blockIdx.x;
  const int w = threadIdx.x >> 6;
  const int c = threadIdx.x & 63;
  const int tid = threadIdx.x;

  __shared__ __align__(16) float hS[22 * 64];  // h rows: 0=R, 1-10=O, 11-21=D
  __shared__ __align__(16) float nS[22 * 64];  // staged n, same row order
  __shared__ __align__(16) float gS[22 * 64];  // h*r staging; X stage at init
  __shared__ float sA2[ANUM];
  __shared__ float red[16];

  const float4* pk = (const float4*)(ws + 1024);
  const float4* pWzR = pk + 0   * 64;
  const float4* pWrR = pk + 32  * 64;
  const float4* pWmR = pk + 64  * 64;
  const float4* pWzO = pk + 96  * 64;
  const float4* pWrO = pk + 144 * 64;
  const float4* pWmO = pk + 192 * 64;
  const float4* pWzD = pk + 240 * 64;
  const float4* pWrD = pk + 272 * 64;
  const float4* pWmD = pk + 304 * 64;

  const float* Xb = X + (size_t)b * 880;
  const float* Ab = A + (size_t)b * 484;
  for (int t = tid; t < 880; t += 256) gS[t] = Xb[t];
  if (tid < 10) {
    sA2[AROB + tid] = Ab[1 + tid];
    sA2[AORB + tid] = Ab[(1 + tid) * 22];
  }
  for (int t = tid; t < 110; t += 256) {
    const int i = t / 11, j = t - i * 11;
    sA2[AODB + t] = Ab[(1 + i) * 22 + 11 + j];
  }
  for (int t = tid; t < 110; t += 256) {
    const int i = t / 10, j = t - i * 10;
    sA2[ADOB + t] = Ab[(11 + i) * 22 + 1 + j];
  }
  __syncthreads();

  // ---------------- phase 0: h = tanh(Xg @ Wg + bg), rows per wave ----------
  if (w == 0 || w == 1) {
    float cO = bgO[c];
#pragma unroll 4
    for (int k = 0; k < 40; ++k) cO = fmaf(gS[k], WgO[k * 64 + c], cO);
    float a0 = cO, a1 = cO, a2 = cO, a3 = cO, a4 = cO;
    const int r0 = (w == 0) ? 1 : 6;  // first global row
#pragma unroll 2
    for (int k = 0; k < 30; ++k) {
      const float wo_ = WgO[(40 + k) * 64 + c];
      a0 = fmaf(gS[(r0 + 0) * 40 + 10 + k], wo_, a0);
      a1 = fmaf(gS[(r0 + 1) * 40 + 10 + k], wo_, a1);
      a2 = fmaf(gS[(r0 + 2) * 40 + 10 + k], wo_, a2);
      a3 = fmaf(gS[(r0 + 3) * 40 + 10 + k], wo_, a3);
      a4 = fmaf(gS[(r0 + 4) * 40 + 10 + k], wo_, a4);
    }
    hS[(r0 + 0) * 64 + c] = tanhf(a0);
    hS[(r0 + 1) * 64 + c] = tanhf(a1);
    hS[(r0 + 2) * 64 + c] = tanhf(a2);
    hS[(r0 + 3) * 64 + c] = tanhf(a3);
    hS[(r0 + 4) * 64 + c] = tanhf(a4);
  } else {
    float cD = bgD[c];
#pragma unroll 4
    for (int k = 0; k < 40; ++k) cD = fmaf(gS[k], WgD[k * 64 + c], cD);
    if (w == 2) {
      float a0 = cD, a1 = cD, a2 = cD, a3 = cD, a4 = cD, a5 = cD;
#pragma unroll 2
      for (int k = 0; k < 30; ++k) {
        const float wd_ = WgD[(40 + k) * 64 + c];
        a0 = fmaf(gS[11 * 40 + 10 + k], wd_, a0);
        a1 = fmaf(gS[12 * 40 + 10 + k], wd_, a1);
        a2 = fmaf(gS[13 * 40 + 10 + k], wd_, a2);
        a3 = fmaf(gS[14 * 40 + 10 + k], wd_, a3);
        a4 = fmaf(gS[15 * 40 + 10 + k], wd_, a4);
        a5 = fmaf(gS[16 * 40 + 10 + k], wd_, a5);
      }
      hS[11 * 64 + c] = tanhf(a0); hS[12 * 64 + c] = tanhf(a1);
      hS[13 * 64 + c] = tanhf(a2); hS[14 * 64 + c] = tanhf(a3);
      hS[15 * 64 + c] = tanhf(a4); hS[16 * 64 + c] = tanhf(a5);
    } else {
      float a0 = cD, a1 = cD, a2 = cD, a3 = cD, a4 = cD;
#pragma unroll 2
      for (int k = 0; k < 30; ++k) {
        const float wd_ = WgD[(40 + k) * 64 + c];
        a0 = fmaf(gS[17 * 40 + 10 + k], wd_, a0);
        a1 = fmaf(gS[18 * 40 + 10 + k], wd_, a1);
        a2 = fmaf(gS[19 * 40 + 10 + k], wd_, a2);
        a3 = fmaf(gS[20 * 40 + 10 + k], wd_, a3);
        a4 = fmaf(gS[21 * 40 + 10 + k], wd_, a4);
      }
      hS[17 * 64 + c] = tanhf(a0); hS[18 * 64 + c] = tanhf(a1);
      hS[19 * 64 + c] = tanhf(a2); hS[20 * 64 + c] = tanhf(a3);
      hS[21 * 64 + c] = tanhf(a4);
      float aR = bgR[c];
#pragma unroll 4
      for (int k = 0; k < 40; ++k) aR = fmaf(gS[k], WgR[k * 64 + c], aR);
      hS[c] = tanhf(aR);
    }
  }
  __syncthreads();

  const float bmOc = bmO[c], bmDc = bmD[c], bmRc = bmR[c];
  float zS0 = 0.f, zS1 = 0.f, zS2 = 0.f, zS3 = 0.f, zS4 = 0.f, zS5 = 0.f;
  float aS0 = 0.f, aS1 = 0.f, aS2 = 0.f, aS3 = 0.f, aS4 = 0.f, aS5 = 0.f;

  // ---------------- 3 GRU iterations ----------------
  for (int it = 0; it < 3; ++it) {
    // (a) stage n (reads OLD hS across waves; writes own nS rows)
    if (w == 0 || w == 1) {
      const float hd0 = hS[11*64+c], hd1 = hS[12*64+c], hd2 = hS[13*64+c], hd3 = hS[14*64+c];
      const float hd4 = hS[15*64+c], hd5 = hS[16*64+c], hd6 = hS[17*64+c], hd7 = hS[18*64+c];
      const float hd8 = hS[19*64+c], hd9 = hS[20*64+c], hd10 = hS[21*64+c];
      if (w == 0) { L5A(NSO) } else { L5B(NSO) }
    } else {
      const float ho0 = hS[1*64+c], ho1 = hS[2*64+c], ho2 = hS[3*64+c], ho3 = hS[4*64+c];
      const float ho4 = hS[5*64+c], ho5 = hS[6*64+c], ho6 = hS[7*64+c], ho7 = hS[8*64+c];
      const float ho8 = hS[9*64+c], ho9 = hS[10*64+c];
      if (w == 2) { L6A(NSD) }
      else {
        L5D(NSD)
        nS[c] = sA2[AROB+0]*ho0 + sA2[AROB+1]*ho1 + sA2[AROB+2]*ho2 + sA2[AROB+3]*ho3
              + sA2[AROB+4]*ho4 + sA2[AROB+5]*ho5 + sA2[AROB+6]*ho6 + sA2[AROB+7]*ho7
              + sA2[AROB+8]*ho8 + sA2[AROB+9]*ho9;
      }
    }

    // (b-d) gate matvecs (all reads of OLD h; own rows + hS[0] broadcast)
    if (w == 0)      { OGATE(L5A) }
    else if (w == 1) { OGATE(L5B) }
    else if (w == 2) { DGATE(L6A) }
    else {
      DGATE(L5D)
      { // gate R -> slot 5
        float azr = 0.f, arr = 0.f;
#pragma unroll 2
        for (int kb = 0; kb < 16; ++kb) {
          const float4 wz = pWzR[kb*64+c], wr = pWrR[kb*64+c];
          const float4 v = *reinterpret_cast<const float4*>(&hS[kb*4]);
          azr=fmaf(v.x,wz.x,azr); azr=fmaf(v.y,wz.y,azr); azr=fmaf(v.z,wz.z,azr); azr=fmaf(v.w,wz.w,azr);
          arr=fmaf(v.x,wr.x,arr); arr=fmaf(v.y,wr.y,arr); arr=fmaf(v.z,wr.z,arr); arr=fmaf(v.w,wr.w,arr);
        }
#pragma unroll 2
        for (int kb = 16; kb < 32; ++kb) {
          const float4 wz = pWzR[kb*64+c], wr = pWrR[kb*64+c];
          const float4 v = *reinterpret_cast<const float4*>(&nS[(kb-16)*4]);
          azr=fmaf(v.x,wz.x,azr); azr=fmaf(v.y,wz.y,azr); azr=fmaf(v.z,wz.z,azr); azr=fmaf(v.w,wz.w,azr);
          arr=fmaf(v.x,wr.x,arr); arr=fmaf(v.y,wr.y,arr); arr=fmaf(v.z,wr.z,arr); arr=fmaf(v.w,wr.w,arr);
        }
        zS5 = sigmoidf_(azr);
        const float r5 = sigmoidf_(arr);
        gS[c] = hS[c] * r5;
        aS5 = bmRc;
#pragma unroll 2
        for (int kb = 0; kb < 16; ++kb) {
          const float4 wm = pWmR[kb*64+c];
          const float4 v = *reinterpret_cast<const float4*>(&gS[kb*4]);
          aS5=fmaf(v.x,wm.x,aS5); aS5=fmaf(v.y,wm.y,aS5); aS5=fmaf(v.z,wm.z,aS5); aS5=fmaf(v.w,wm.w,aS5);
        }
#pragma unroll 2
        for (int kb = 16; kb < 32; ++kb) {
          const float4 wm = pWmR[kb*64+c];
          const float4 v = *reinterpret_cast<const float4*>(&nS[(kb-16)*4]);
          aS5=fmaf(v.x,wm.x,aS5); aS5=fmaf(v.y,wm.y,aS5); aS5=fmaf(v.z,wm.z,aS5); aS5=fmaf(v.w,wm.w,aS5);
        }
      }
    }

    __syncthreads();  // all old-h reads complete before any h-write

    // (e) update own h rows
    if (w == 0)      { L5A(OUPD) }
    else if (w == 1) { L5B(OUPD) }
    else if (w == 2) { L6A(DUPD) }
    else {
      L5D(DUPD)
      { const float h_ = hS[c]; hS[c] = (1.f - zS5) * h_ + zS5 * tanhf(aS5); }
    }
    __syncthreads();  // new h visible
  }

  // ---------------- scores (rows per wave) ----------------
  const int g = c >> 4;
  const int c1 = c & 15;
  float pR = 0.f, pO = 0.f, pD = 0.f;
  int lo, hi;
  if      (w == 0) { lo = 1;  hi = 6;  }
  else if (w == 1) { lo = 6;  hi = 11; }
  else if (w == 2) { lo = 11; hi = 17; }
  else             { lo = 17; hi = 22; }
  for (int rr = lo + g; rr < hi; rr += 4) {
    const float* W1; const float* b1; const float* W2;
    if (rr < 11) { W1 = W1O; b1 = b1O; W2 = W2O; }
    else         { W1 = W1D; b1 = b1D; W2 = W2D; }
    float a = b1[c1];
#pragma unroll 8
    for (int kk = 0; kk < 64; ++kk) {
      const int k = (kk + (g << 4)) & 63;
      a = fmaf(hS[rr * 64 + k], W1[k * 16 + c1], a);
    }
    const float t = tanhf(a) * W2[c1];
    if (rr < 11) pO += t;
    else pD += t;
  }
  if (w == 3 && g == 0) {  // row 0 (R branch)
    float a = b1R[c1];
#pragma unroll 8
    for (int kk = 0; kk < 64; ++kk) {
      a = fmaf(hS[kk], W1R[kk * 16 + c1], a);
    }
    pR = tanhf(a) * W2R[c1];
  }
#pragma unroll
  for (int off = 32; off >= 1; off >>= 1) {
    pR += __shfl_xor(pR, off, 64);
    pO += __shfl_xor(pO, off, 64);
    pD += __shfl_xor(pD, off, 64);
  }
  if (c == 0) { red[w * 4 + 0] = pR; red[w * 4 + 1] = pO; red[w * 4 + 2] = pD; }
  __syncthreads();
  if (w == 0 && c < 60) {
    const float PR = red[0] + red[4] + red[8]  + red[12];
    const float PO = red[1] + red[5] + red[9]  + red[13];
    const float PD = red[2] + red[6] + red[10] + red[14];
    out[(size_t)b * 60 + c] = PR * tp[c] + PO * tp[60 + c] + PD * tp[120 + c];
  }
}

extern "C" void kernel_launch(void* const* d_in, const int* in_sizes, int n_in,
                              void* d_out, int out_size, void* d_ws, size_t ws_size,
                              hipStream_t stream) {
  const float* X   = (const float*)d_in[0];
  const float* A   = (const float*)d_in[1];
  const float* WgR = (const float*)d_in[2];
  const float* bgR = (const float*)d_in[3];
  const float* WgO = (const float*)d_in[4];
  const float* bgO = (const float*)d_in[5];
  const float* WgD = (const float*)d_in[6];
  const float* bgD = (const float*)d_in[7];
  const float* WzR = (const float*)d_in[8];
  const float* WrR = (const float*)d_in[9];
  const float* WmR = (const float*)d_in[10];
  const float* bmR = (const float*)d_in[11];
  const float* WzO = (const float*)d_in[12];
  const float* WrO = (const float*)d_in[13];
  const float* WmO = (const float*)d_in[14];
  const float* bmO = (const float*)d_in[15];
  const float* WzD = (const float*)d_in[16];
  const float* WrD = (const float*)d_in[17];
  const float* WmD = (const float*)d_in[18];
  const float* bmD = (const float*)d_in[19];
  const float* W1R = (const float*)d_in[20];
  const float* b1R = (const float*)d_in[21];
  const float* W2R = (const float*)d_in[22];
  const float* W1O = (const float*)d_in[23];
  const float* b1O = (const float*)d_in[24];
  const float* W2O = (const float*)d_in[25];
  const float* W1D = (const float*)d_in[26];
  const float* b1D = (const float*)d_in[27];
  const float* W2D = (const float*)d_in[28];
  const float* Tmp = (const float*)d_in[29];
  const float* GK  = (const float*)d_in[30];
  const float* GRK = (const float*)d_in[31];
  const float* GB  = (const float*)d_in[32];
  const float* WO  = (const float*)d_in[33];
  const int*   IDX = (const int*)d_in[34];

  float* tp = (float*)d_ws;  // 3*60 floats in the first 1KB
  char*  ws = (char*)d_ws;
  const int B = in_sizes[0] / 880;

  hipLaunchKernelGGL(temporal_kernel, dim3(1), dim3(64), 0, stream, Tmp, GK, GRK, GB, WO, IDX, tp);
  hipLaunchKernelGGL(prep_kernel, dim3(336), dim3(64), 0, stream,
                     WzR, WrR, WmR, WzO, WrO, WmO, WzD, WrD, WmD, ws);
  hipLaunchKernelGGL(ggnn_main, dim3(B), dim3(256), 0, stream,
                     X, A, WgR, bgR, WgO, bgO, WgD, bgD,
                     bmR, bmO, bmD,
                     W1R, b1R, W2R, W1O, b1O, W2O, W1D, b1D, W2D,
                     (const char*)ws, (const float*)tp, (float*)d_out);
}